// Round 9
// baseline (450.236 us; speedup 1.0000x reference)
//
#include <hip/hip_runtime.h>

#define TPB 256  // 4 independent waves per block; wave = 32 rows

typedef _Float16 f16x8 __attribute__((ext_vector_type(8)));
typedef __fp16 h16x2 __attribute__((ext_vector_type(2)));  // cvt_pkrtz native type
typedef float f32x16 __attribute__((ext_vector_type(16)));

// fp16 weight tiles (32x32x16 B-fragment order), element offsets per plane:
// tile(c, qt) = 512 f16 (1KB). L0: NC=32 -> 65536 ; L1-3: NC=64 -> 131072 each
static constexpr int WT_L0 = 0;
static constexpr int WT_L1 = 65536;
static constexpr int WT_L2 = 196608;
static constexpr int WT_L3 = 327680;
static constexpr int WT_END = 458752;          // f16 elements per plane
static constexpr int F32_BASE = WT_END;        // float offset into ws (2 f16 planes)
static constexpr int MST2 = 33;                // mT row stride (floats), conflict-free

// ---------- helpers ----------
__device__ __forceinline__ float fast_tanh2(float x) {  // 2*tanh(x)
  float e = __expf(2.0f * x);
  return fmaf(-4.0f, __builtin_amdgcn_rcpf(e + 1.0f), 2.0f);
}
__device__ __forceinline__ float gelu_exact(float v) {
  return 0.5f * v * (1.0f + erff(v * 0.70710678f));
}

// ---------- fusion kernels ----------
// within-tile element e = lane*8 + j ; lane = g*32 + q (g = k-group, q = col)
// e = g*256 + q*8 + j ; k = g*8 + j ; p = 2c + g ; n = j+1 ; out col = qt*32 + q
__global__ void fuse_w_f16(const float* __restrict__ W, const float* __restrict__ tW,
                           _Float16* __restrict__ out_hi, _Float16* __restrict__ out_lo,
                           int P, int total) {
  int i = blockIdx.x * 256 + threadIdx.x;
  if (i >= total) return;
  int j = i & 7, q = (i >> 3) & 31, g = (i >> 8) & 1, qt = (i >> 9) & 3, c = i >> 11;
  int p = 2 * c + g;
  int qg = qt * 32 + q;
  float v = tW[(qg * P + p) * 9 + (j + 1)] * W[qg * P + p];
  _Float16 hi = (_Float16)v;
  out_hi[i] = hi;
  out_lo[i] = (_Float16)(v - (float)hi);
}
// bias[q] = sum_p tW[q,p,0]*W[q,p]   (the n=0 / T0=1 term)
__global__ void fuse_bias(const float* __restrict__ W, const float* __restrict__ tW,
                          float* __restrict__ bias, int P, int Q) {
  int q = blockIdx.x * 64 + threadIdx.x;
  if (q >= Q) return;
  float s = 0.0f;
  for (int p = 0; p < P; ++p) s += tW[(q * P + p) * 9] * W[q * P + p];
  bias[q] = s;
}
// w4[p*9+n] = tW4[p*9+n] * W4[p]
__global__ void fuse_w4(const float* __restrict__ W, const float* __restrict__ tW,
                        float* __restrict__ out) {
  int i = blockIdx.x * 128 + threadIdx.x;
  if (i >= 1152) return;
  out[i] = tW[i] * W[i / 9];
}

// ---------- per-layer 32x32x16 MFMA, split precision, B prefetch ----------
// mT[p*MST2 + r] holds m = 2tanh(h_in); acc[qt] C/D: col=qt*32+(l&31),
// row=(r&3)+8*(r>>2)+4*(l>>5)
template <int P, bool RES>
__device__ __forceinline__ void layer32(const float* __restrict__ mT,
                                        const _Float16* __restrict__ wt_hi,
                                        const _Float16* __restrict__ wt_lo,
                                        const float* __restrict__ bias,
                                        f32x16 (&acc)[4], int l) {
  const int c31 = l & 31, g = l >> 5;
#pragma unroll
  for (int qt = 0; qt < 4; ++qt) {
    float bv = bias[qt * 32 + c31];
#pragma unroll
    for (int r = 0; r < 16; ++r) {
      if (RES) acc[qt][r] += bv; else acc[qt][r] = bv;
    }
  }
  const _Float16* slot_hi = wt_hi + l * 8;  // lane's 16B slot within each 1KB tile
  const _Float16* slot_lo = wt_lo + l * 8;
  constexpr int NC = P / 2;

  f16x8 b0h[4], b0l[4], b1h[4], b1l[4];
  f16x8 ah, al;

#define LOADB(dh, dl, c)                                                      \
  {                                                                           \
    const _Float16* bh_ = slot_hi + (size_t)(c) * 2048;                       \
    const _Float16* bl_ = slot_lo + (size_t)(c) * 2048;                       \
    _Pragma("unroll") for (int qt = 0; qt < 4; ++qt) {                        \
      dh[qt] = *(const f16x8*)(bh_ + qt * 512);                               \
      dl[qt] = *(const f16x8*)(bl_ + qt * 512);                               \
    }                                                                         \
  }

#define AFRAG(c)                                                              \
  {                                                                           \
    float m_ = mT[(2 * (c) + g) * MST2 + c31];                                \
    float t_[8];                                                              \
    t_[0] = m_;                                                               \
    float u0_ = 1.0f, u1_ = m_;                                               \
    _Pragma("unroll") for (int n = 2; n <= 8; ++n) {                          \
      float u_ = fmaf(m_, u1_, -u0_);                                         \
      u0_ = u1_;                                                              \
      u1_ = u_;                                                               \
      t_[n - 1] = u_;                                                         \
    }                                                                         \
    union U8 { h16x2 h2[4]; f16x8 v; } uh_, ul_;                              \
    _Pragma("unroll") for (int ii = 0; ii < 4; ++ii) {                        \
      float v0 = t_[2 * ii], v1 = t_[2 * ii + 1];                             \
      h16x2 h_ = __builtin_amdgcn_cvt_pkrtz(v0, v1);                          \
      uh_.h2[ii] = h_;                                                        \
      ul_.h2[ii] =                                                            \
          __builtin_amdgcn_cvt_pkrtz(v0 - (float)h_[0], v1 - (float)h_[1]);   \
    }                                                                         \
    ah = uh_.v;                                                               \
    al = ul_.v;                                                               \
  }

#define MFMA12(bh, bl)                                                        \
  {                                                                           \
    __builtin_amdgcn_s_setprio(1);                                            \
    _Pragma("unroll") for (int qt = 0; qt < 4; ++qt)                          \
        acc[qt] = __builtin_amdgcn_mfma_f32_32x32x16_f16(ah, bh[qt],          \
                                                         acc[qt], 0, 0, 0);   \
    _Pragma("unroll") for (int qt = 0; qt < 4; ++qt)                          \
        acc[qt] = __builtin_amdgcn_mfma_f32_32x32x16_f16(al, bh[qt],          \
                                                         acc[qt], 0, 0, 0);   \
    _Pragma("unroll") for (int qt = 0; qt < 4; ++qt)                          \
        acc[qt] = __builtin_amdgcn_mfma_f32_32x32x16_f16(ah, bl[qt],          \
                                                         acc[qt], 0, 0, 0);   \
    __builtin_amdgcn_s_setprio(0);                                            \
  }

  LOADB(b0h, b0l, 0);
#pragma unroll 1
  for (int cc = 0; cc < NC; cc += 2) {
    AFRAG(cc);
    LOADB(b1h, b1l, cc + 1);
    MFMA12(b0h, b0l);
    AFRAG(cc + 1);
    if (cc + 2 < NC) LOADB(b0h, b0l, cc + 2);
    MFMA12(b1h, b1l);
  }
#undef LOADB
#undef AFRAG
#undef MFMA12
}

// write m = 2tanh(acc) into mT[p][r] from 32x32 C-layout frags
__device__ __forceinline__ void write_m32(float* __restrict__ mT,
                                          const f32x16 (&acc)[4], int l) {
  const int c31 = l & 31, g = l >> 5;
#pragma unroll
  for (int qt = 0; qt < 4; ++qt)
#pragma unroll
    for (int r = 0; r < 16; ++r) {
      int row = (r & 3) + 8 * (r >> 2) + 4 * g;
      mT[(qt * 32 + c31) * MST2 + row] = fast_tanh2(acc[qt][r]);
    }
}

// ---------- main kernel: zero barriers, waves independent ----------
__global__ void __launch_bounds__(TPB, 2)
kan_mfma(const float* __restrict__ x, const float* __restrict__ Bm,
         const _Float16* __restrict__ wt_hi, const _Float16* __restrict__ wt_lo,
         const float* __restrict__ bias, const float* __restrict__ w4,
         float* __restrict__ out) {
  __shared__ float mT_all[4][128 * MST2];  // 66 KB total
  int tid = threadIdx.x;
  int l = tid & 63;
  int w = tid >> 6;
  float* mT = mT_all[w];
  int row0 = blockIdx.x * 128 + w * 32;

  // ---- Fourier features -> mT for L0 (p = channel, r = batch row) ----
  {
    int r = l & 31, hh = l >> 5;
    const float4* xp = (const float4*)(x + (size_t)(row0 + r) * 8);
    float4 a = xp[0], c4 = xp[1];
    float xv[8] = {a.x, a.y, a.z, a.w, c4.x, c4.y, c4.z, c4.w};
#pragma unroll
    for (int jj = 0; jj < 16; ++jj) {
      int j = hh * 16 + jj;
      float pr = 0.0f;
#pragma unroll
      for (int k = 0; k < 8; ++k) pr = fmaf(xv[k], Bm[k * 32 + j], pr);
      float ang = 6.2831853071795864f * pr;
      float sv, cv;
      sincosf(ang, &sv, &cv);
      mT[j * MST2 + r] = fast_tanh2(sv);
      mT[(32 + j) * MST2 + r] = fast_tanh2(cv);
    }
  }

  f32x16 acc[4];
  layer32<64, false>(mT, wt_hi + WT_L0, wt_lo + WT_L0, bias + 0, acc, l);
  write_m32(mT, acc, l);
  layer32<128, true>(mT, wt_hi + WT_L1, wt_lo + WT_L1, bias + 128, acc, l);
  write_m32(mT, acc, l);
  layer32<128, true>(mT, wt_hi + WT_L2, wt_lo + WT_L2, bias + 256, acc, l);
  write_m32(mT, acc, l);
  layer32<128, true>(mT, wt_hi + WT_L3, wt_lo + WT_L3, bias + 384, acc, l);
  write_m32(mT, acc, l);

  // ---- L4: 128 -> 1 (fp32 scalar, split p-halves across half-waves) ----
  {
    int r = l & 31, ph = l >> 5;
    const float* w4h = w4 + ph * 64 * 9;
    float part = 0.0f;
#pragma unroll 4
    for (int pp = 0; pp < 64; ++pp) {
      float mm = mT[(ph * 64 + pp) * MST2 + r];
      const float* wp = w4h + pp * 9;
      part += wp[0];
      part = fmaf(mm, wp[1], part);
      float u2 = 1.0f, u1 = mm;
#pragma unroll
      for (int n = 2; n < 9; ++n) {
        float u = fmaf(mm, u1, -u2);
        u2 = u1;
        u1 = u;
        part = fmaf(u, wp[n], part);
      }
    }
    part += __shfl_xor(part, 32);
    if (l < 32) {
      float v = part;
      // cheby-gelu, degree 5, T1 = tanh(v)
      float t = 0.5f * fast_tanh2(v);
      float m2 = t + t;
      float tm2 = 1.0f, tm1 = t;
      float y = gelu_exact(1.0f) + gelu_exact(t);
#pragma unroll
      for (int n = 2; n <= 5; ++n) {
        float tn = fmaf(m2, tm1, -tm2);
        tm2 = tm1;
        tm1 = tn;
        y += gelu_exact(tn);
      }
      out[row0 + r] = y;
    }
  }
}

extern "C" void kernel_launch(void* const* d_in, const int* in_sizes, int n_in,
                              void* d_out, int out_size, void* d_ws, size_t ws_size,
                              hipStream_t stream) {
  const float* x   = (const float*)d_in[0];
  const float* Bm  = (const float*)d_in[1];
  const float* W0  = (const float*)d_in[2];
  const float* tW0 = (const float*)d_in[3];
  const float* W1  = (const float*)d_in[4];
  const float* tW1 = (const float*)d_in[5];
  const float* W2  = (const float*)d_in[6];
  const float* tW2 = (const float*)d_in[7];
  const float* W3  = (const float*)d_in[8];
  const float* tW3 = (const float*)d_in[9];
  const float* W4  = (const float*)d_in[10];
  const float* tW4 = (const float*)d_in[11];

  _Float16* wt_hi = (_Float16*)d_ws;
  _Float16* wt_lo = wt_hi + WT_END;
  float* fws = (float*)d_ws + F32_BASE;
  float* bias = fws;        // 4*128 floats
  float* w4 = fws + 512;    // 1152 floats

  fuse_w_f16<<<65536 / 256, 256, 0, stream>>>(W0, tW0, wt_hi + WT_L0, wt_lo + WT_L0, 64, 65536);
  fuse_w_f16<<<131072 / 256, 256, 0, stream>>>(W1, tW1, wt_hi + WT_L1, wt_lo + WT_L1, 128, 131072);
  fuse_w_f16<<<131072 / 256, 256, 0, stream>>>(W2, tW2, wt_hi + WT_L2, wt_lo + WT_L2, 128, 131072);
  fuse_w_f16<<<131072 / 256, 256, 0, stream>>>(W3, tW3, wt_hi + WT_L3, wt_lo + WT_L3, 128, 131072);
  fuse_bias<<<2, 64, 0, stream>>>(W0, tW0, bias + 0, 64, 128);
  fuse_bias<<<2, 64, 0, stream>>>(W1, tW1, bias + 128, 128, 128);
  fuse_bias<<<2, 64, 0, stream>>>(W2, tW2, bias + 256, 128, 128);
  fuse_bias<<<2, 64, 0, stream>>>(W3, tW3, bias + 384, 128, 128);
  fuse_w4<<<9, 128, 0, stream>>>(W4, tW4, w4);

  kan_mfma<<<131072 / 128, TPB, 0, stream>>>(x, Bm, wt_hi, wt_lo, bias, w4, (float*)d_out);
}